// Round 5
// baseline (1434.963 us; speedup 1.0000x reference)
//
#include <hip/hip_runtime.h>
#include <hip/hip_bf16.h>
#include <stdint.h>
#include <math.h>

#define DM 1024
#define DH 2048
#define NB 4
#define SL 4096
#define MT (NB*SL)   // 16384 rows

typedef __bf16 bf16;
typedef __attribute__((ext_vector_type(8))) __bf16 bf16x8;
typedef __attribute__((ext_vector_type(4))) float f32x4;

// ===========================================================================
// fp32 -> bf16 sanitizing convert (NaN -> 0, clamp +-65504). Grid-stride.
// Sanitize establishes the finite-inputs invariant: downstream cannot mint
// NaN from finite inputs, so the failure mode of a wrong dtype hypothesis is
// a finite-huge absmax (diagnostic), never NaN.
// ===========================================================================
__global__ void cvt_kernel(const float* __restrict__ in, bf16* __restrict__ out, int n) {
  for (int i = blockIdx.x * 256 + threadIdx.x; i < n; i += gridDim.x * 256) {
    float v = in[i];
    v = (v == v) ? fminf(fmaxf(v, -65504.f), 65504.f) : 0.f;
    out[i] = (bf16)v;
  }
}

// ===========================================================================
// GEMM: out[M,N] = A[M,K] @ W[N,K]^T (+bias) with fused epilogues.
// A, W are bf16 (pre-converted); bias is fp32.
// 128x128 tile, BK=64, 4 waves (2x2 of 64x64), mfma_f32_16x16x32_bf16.
// Staging: VGPR round-trip (global 16B vector load -> ds_write_b128).
// LDS layout: 16B slot index = row*8 + kc (row-major, no pad, no swizzle).
// MODE 0: out_bf16 = acc (+bias)
// MODE 1: out_f32  = acc + bias
// MODE 2: out_bf16 = acc + bias + extra_f32[off]
// MODE 3: out_bf16 = extra_bf16[off] * silu(acc)            (z-gate)
// MODE 4: out_f32  = acc + extra_bf16[off]                  (residual, final)
// MODE 5: out_bf16 = softplus(acc + bias)                   (delta)
// MODE 6: out_bf16 = extra_bf16[off] * (acc + bias)         (nla = delta*A_t)
// ===========================================================================
template<int MODE, bool HAS_BIAS>
__global__ __launch_bounds__(256, 2)
void gemm_bt(const bf16* __restrict__ A, const bf16* __restrict__ W,
             const float* __restrict__ bias, const void* __restrict__ extra,
             void* __restrict__ outp, int M, int N, int K) {
  __shared__ __align__(16) bf16 lds_a[128*64];
  __shared__ __align__(16) bf16 lds_b[128*64];
  const int tid  = threadIdx.x;
  const int wave = tid >> 6;
  const int lane = tid & 63;
  const int wm = wave >> 1, wn = wave & 1;
  const int bm = blockIdx.y, bn = blockIdx.x;

  const int r_in = lane >> 3;             // row within 8-row chunk
  const int kc_l = lane & 7;              // 16B k-chunk this lane stages
  const size_t arow0 = (size_t)bm * 128;
  const size_t brow0 = (size_t)bn * 128;

  f32x4 acc[4][4];
#pragma unroll
  for (int i = 0; i < 4; ++i)
#pragma unroll
    for (int j = 0; j < 4; ++j) acc[i][j] = {0.f, 0.f, 0.f, 0.f};

  const int mrow = lane & 15;
  const int kg   = lane >> 4;

  for (int k0 = 0; k0 < K; k0 += 64) {
    bf16x8 va[4], vb[4];
#pragma unroll
    for (int iss = 0; iss < 4; ++iss) {
      const int chunk = iss * 4 + wave;        // 16 chunks of 8 rows
      const int row   = chunk * 8 + r_in;
      va[iss] = *(const bf16x8*)(A + (arow0 + row) * (size_t)K + (k0 + kc_l * 8));
      vb[iss] = *(const bf16x8*)(W + (brow0 + row) * (size_t)K + (k0 + kc_l * 8));
    }
    __syncthreads();  // previous tile's LDS reads complete before overwrite
#pragma unroll
    for (int iss = 0; iss < 4; ++iss) {
      const int chunk = iss * 4 + wave;
      *(bf16x8*)&lds_a[chunk * 512 + lane * 8] = va[iss];
      *(bf16x8*)&lds_b[chunk * 512 + lane * 8] = vb[iss];
    }
    __syncthreads();
#pragma unroll
    for (int ks = 0; ks < 2; ++ks) {
      bf16x8 af[4], bfr[4];
#pragma unroll
      for (int t = 0; t < 4; ++t) {
        const int ra = wm * 64 + t * 16 + mrow;
        af[t] = *(const bf16x8*)&lds_a[(ra * 8 + ks * 4 + kg) * 8];
        const int rb = wn * 64 + t * 16 + mrow;
        bfr[t] = *(const bf16x8*)&lds_b[(rb * 8 + ks * 4 + kg) * 8];
      }
#pragma unroll
      for (int i = 0; i < 4; ++i)
#pragma unroll
        for (int j = 0; j < 4; ++j)
          acc[i][j] = __builtin_amdgcn_mfma_f32_16x16x32_bf16(af[i], bfr[j], acc[i][j], 0, 0, 0);
    }
  }

  // Epilogue. C/D layout: col = lane&15, row = (lane>>4)*4 + reg.
#pragma unroll
  for (int j = 0; j < 4; ++j) {
    const int col = bn * 128 + wn * 64 + j * 16 + mrow;
    float bv = 0.f;
    if constexpr (HAS_BIAS) bv = bias[col];
#pragma unroll
    for (int i = 0; i < 4; ++i) {
      const int row0 = bm * 128 + wm * 64 + i * 16 + kg * 4;
#pragma unroll
      for (int r = 0; r < 4; ++r) {
        const size_t off = (size_t)(row0 + r) * N + col;
        float v = acc[i][j][r] + bv;
        if constexpr (MODE == 0) {
          ((bf16*)outp)[off] = (bf16)v;
        } else if constexpr (MODE == 1) {
          ((float*)outp)[off] = v;
        } else if constexpr (MODE == 2) {
          ((bf16*)outp)[off] = (bf16)(v + ((const float*)extra)[off]);
        } else if constexpr (MODE == 3) {
          const float g = (float)((const bf16*)extra)[off];
          const float s = v / (1.f + expf(-v));
          ((bf16*)outp)[off] = (bf16)(g * s);
        } else if constexpr (MODE == 4) {
          ((float*)outp)[off] = v + (float)((const bf16*)extra)[off];
        } else if constexpr (MODE == 5) {
          const float sp = (v > 15.f) ? v : log1pf(expf(v));
          ((bf16*)outp)[off] = (bf16)sp;
        } else {  // MODE 6
          const float d = (float)((const bf16*)extra)[off];
          ((bf16*)outp)[off] = (bf16)(d * v);
        }
      }
    }
  }
}

// ===========================================================================
// depthwise conv1d(k=3, pad=1 along L, per-batch) + bias + silu. 8 d's/thread.
// t1 bf16; conv weights/bias read directly as fp32.
// ===========================================================================
__global__ void conv_silu_kernel(const bf16* __restrict__ t1, const float* __restrict__ cw,
                                 const float* __restrict__ cb, bf16* __restrict__ xc) {
  const int gid  = blockIdx.x * 256 + threadIdx.x;   // MT*DM/8 threads
  const int dgrp = gid & (DM / 8 - 1);
  const int bl   = gid >> 7;
  const int l    = bl & (SL - 1);
  const int d0   = dgrp * 8;
  const bf16* p  = t1 + (size_t)bl * DM + d0;
  bf16x8 cc = *(const bf16x8*)p;
  bf16x8 lf, rt;
#pragma unroll
  for (int j = 0; j < 8; ++j) { lf[j] = (bf16)0.f; rt[j] = (bf16)0.f; }
  if (l > 0)      lf = *(const bf16x8*)(p - DM);
  if (l < SL - 1) rt = *(const bf16x8*)(p + DM);
  bf16x8 o;
#pragma unroll
  for (int j = 0; j < 8; ++j) {
    const int d = d0 + j;
    float y = cw[d * 3 + 0] * (float)lf[j] + cw[d * 3 + 1] * (float)cc[j]
            + cw[d * 3 + 2] * (float)rt[j] + cb[d];
    y = y / (1.f + expf(-y));
    o[j] = (bf16)y;
  }
  *(bf16x8*)(xc + (size_t)bl * DM + d0) = o;
}

// ===========================================================================
// scan: per (b,h) channel. nla = delta*A_t (bf16). logP in fp32:
// P_l = exp(-sum nla), h_l = sum Bx_i * P_i. h written IN-PLACE over Bx via
// a single (non-restrict) pointer. exp arg clamped (stays finite always).
// ===========================================================================
__global__ void scan_kernel(const bf16* __restrict__ nla, bf16* bxh) {
  const int tid = blockIdx.x * 256 + threadIdx.x;   // 0..8191
  const int b   = tid >> 11;
  const int ch  = tid & (DH - 1);
  const size_t base = (size_t)b * SL * DH + ch;
  float lp = 0.f, S = 0.f;
#pragma unroll 8
  for (int l = 0; l < SL; ++l) {
    const size_t off = base + (size_t)l * DH;
    const float a = (float)nla[off];
    const float x = (float)bxh[off];
    lp += a;
    const float e = expf(-fminf(fmaxf(lp, -80.f), 80.f));
    S = fmaf(x, e, S);
    bxh[off] = (bf16)S;
  }
}

// ===========================================================================
// Workspace layout (max live 184 MB <= proven-safe 192 MB), offsets in MB:
//  W  [  0.. 24): bf16 weights: w1 0-2, w2 2-4, w3 4-6, D_w 6-8,
//                 A_w 8-12, B_w 12-16, dl_w 16-20, C_w 20-24   (persistent)
//  [24..56):  xc (disp 4..9)   -> ssm (disp 10..12)
//  [56..88):  t1 (disp 3..4)   -> part of dlo/bxh -> z (disp 11..12)
//  [88..120): x_bf16 (disp 1..3) -> part of dlo/bxh
//  [56..120): dlo (disp 5..6)  -> bxh (disp 7..10, scan in-place)
//  [120..184): nla (disp 6..8) -> dtmp fp32 (disp 9..10)
// ===========================================================================
extern "C" void kernel_launch(void* const* d_in, const int* in_sizes, int n_in,
                              void* d_out, int out_size, void* d_ws, size_t ws_size,
                              hipStream_t stream) {
  const float* x    = (const float*)d_in[0];
  const float* w1   = (const float*)d_in[1];
  const float* w2   = (const float*)d_in[2];
  const float* w3   = (const float*)d_in[3];
  const float* cw   = (const float*)d_in[4];
  const float* cb   = (const float*)d_in[5];
  const float* A_w  = (const float*)d_in[6];
  const float* A_b  = (const float*)d_in[7];
  const float* B_w  = (const float*)d_in[8];
  const float* B_b  = (const float*)d_in[9];
  const float* C_w  = (const float*)d_in[10];
  const float* C_b  = (const float*)d_in[11];
  const float* D_w  = (const float*)d_in[12];
  const float* D_b  = (const float*)d_in[13];
  const float* dl_w = (const float*)d_in[14];
  const float* dl_b = (const float*)d_in[15];

  const size_t MB = 1048576u;
  char* ws = (char*)d_ws;
  bf16* w1b  = (bf16*)(ws + 0*MB);
  bf16* w2b  = (bf16*)(ws + 2*MB);
  bf16* w3b  = (bf16*)(ws + 4*MB);
  bf16* Dwb  = (bf16*)(ws + 6*MB);
  bf16* Awb  = (bf16*)(ws + 8*MB);
  bf16* Bwb  = (bf16*)(ws + 12*MB);
  bf16* dlwb = (bf16*)(ws + 16*MB);
  bf16* Cwb  = (bf16*)(ws + 20*MB);
  bf16* xc   = (bf16*)(ws + 24*MB);
  bf16* ssm  = xc;
  bf16* t1   = (bf16*)(ws + 56*MB);
  bf16* z    = t1;
  bf16* xbf  = (bf16*)(ws + 88*MB);
  bf16* dlo  = (bf16*)(ws + 56*MB);   // 64 MB
  bf16* bxh  = dlo;                    // B_x, then h in-place
  bf16* nla  = (bf16*)(ws + 120*MB);  // 64 MB
  float* dtmp = (float*)nla;
  float* outp = (float*)d_out;

  dim3 blk(256);
  dim3 g1(DM / 128, MT / 128);   // N=1024
  dim3 g2(DH / 128, MT / 128);   // N=2048

  // --- convert inputs to bf16 (sanitizing) ---
  cvt_kernel<<<4096, blk, 0, stream>>>(x,    xbf,  MT*DM);
  cvt_kernel<<<512,  blk, 0, stream>>>(w1,   w1b,  DM*DM);
  cvt_kernel<<<512,  blk, 0, stream>>>(w2,   w2b,  DM*DM);
  cvt_kernel<<<512,  blk, 0, stream>>>(w3,   w3b,  DM*DM);
  cvt_kernel<<<512,  blk, 0, stream>>>(D_w,  Dwb,  DM*DM);
  cvt_kernel<<<1024, blk, 0, stream>>>(A_w,  Awb,  DH*DM);
  cvt_kernel<<<1024, blk, 0, stream>>>(B_w,  Bwb,  DH*DM);
  cvt_kernel<<<1024, blk, 0, stream>>>(dl_w, dlwb, DH*DM);
  cvt_kernel<<<1024, blk, 0, stream>>>(C_w,  Cwb,  DM*DH);

  // --- pipeline ---
  gemm_bt<0,false><<<g1, blk, 0, stream>>>(xbf, w1b,  nullptr, nullptr, t1,   MT, DM, DM);
  conv_silu_kernel<<<MT * DM / 8 / 256, blk, 0, stream>>>(t1, cw, cb, xc);
  gemm_bt<5,true ><<<g2, blk, 0, stream>>>(xc,  dlwb, dl_b,    nullptr, dlo,  MT, DH, DM);
  gemm_bt<6,true ><<<g2, blk, 0, stream>>>(xc,  Awb,  A_b,     dlo,     nla,  MT, DH, DM);
  gemm_bt<0,true ><<<g2, blk, 0, stream>>>(xc,  Bwb,  B_b,     nullptr, bxh,  MT, DH, DM);
  scan_kernel<<<NB * DH / 256, blk, 0, stream>>>(nla, bxh);
  gemm_bt<1,true ><<<g1, blk, 0, stream>>>(xc,  Dwb,  D_b,     nullptr, dtmp, MT, DM, DM);
  gemm_bt<2,true ><<<g1, blk, 0, stream>>>(bxh, Cwb,  C_b,     dtmp,    ssm,  MT, DM, DH);
  gemm_bt<3,false><<<g1, blk, 0, stream>>>(ssm, w2b,  nullptr, ssm,     z,    MT, DM, DM);
  gemm_bt<4,false><<<g1, blk, 0, stream>>>(z,   w3b,  nullptr, ssm,     outp, MT, DM, DM);
}

// Round 6
// 1101.289 us; speedup vs baseline: 1.3030x; 1.3030x over previous
//
#include <hip/hip_runtime.h>
#include <hip/hip_bf16.h>
#include <stdint.h>
#include <math.h>

#define DM 1024
#define DH 2048
#define NB 4
#define SL 4096
#define MT (NB*SL)   // 16384 rows
#define LC 256       // scan chunk length
#define NC (SL/LC)   // 16 chunks per channel

typedef __bf16 bf16;
typedef __attribute__((ext_vector_type(8))) __bf16 bf16x8;
typedef __attribute__((ext_vector_type(4))) float f32x4;

// ---- async global->LDS, 16B per lane. LDS dest = wave-uniform base + lane*16.
__device__ __forceinline__ void gl_lds16(const bf16* g, bf16* l) {
  typedef __attribute__((address_space(1))) uint32_t* gp_t;
  typedef __attribute__((address_space(3))) uint32_t* lp_t;
  gp_t gp = (gp_t)(uintptr_t)g;
  lp_t lp = (lp_t)(uint32_t)(uintptr_t)l;
  __builtin_amdgcn_global_load_lds(gp, lp, 16, 0, 0);
}

// ===========================================================================
// fp32 -> bf16 sanitizing convert (NaN -> 0, clamp +-65504). Grid-stride.
// ===========================================================================
__global__ void cvt_kernel(const float* __restrict__ in, bf16* __restrict__ out, int n) {
  for (int i = blockIdx.x * 256 + threadIdx.x; i < n; i += gridDim.x * 256) {
    float v = in[i];
    v = (v == v) ? fminf(fmaxf(v, -65504.f), 65504.f) : 0.f;
    out[i] = (bf16)v;
  }
}

// ===========================================================================
// GEMM: out[M,N] = A[M,K] @ W[N,K]^T (+bias) with fused epilogues.
// A, W bf16 (pre-converted); bias fp32.
// 128x128 tile, BK=64, 4 waves (2x2 of 64x64), mfma_f32_16x16x32_bf16.
// Staging: async global_load_lds width=16 (m97 path, dtype bug exonerated).
// LDS layout: 16B slot index = row*8 + kc (row-major, no pad, no swizzle).
// MODE 0: out_bf16 = acc (+bias)
// MODE 1: out_f32  = acc + bias
// MODE 2: out_bf16 = acc + bias + extra_f32[off]
// MODE 3: out_bf16 = extra_bf16[off] * silu(acc)            (z-gate)
// MODE 4: out_f32  = acc + extra_bf16[off]                  (residual, final)
// MODE 5: out_bf16 = softplus(acc + bias)                   (delta)
// MODE 6: out_bf16 = extra_bf16[off] * (acc + bias)         (nla = delta*A_t)
// ===========================================================================
template<int MODE, bool HAS_BIAS>
__global__ __launch_bounds__(256, 2)
void gemm_bt(const bf16* __restrict__ A, const bf16* __restrict__ W,
             const float* __restrict__ bias, const void* __restrict__ extra,
             void* __restrict__ outp, int M, int N, int K) {
  __shared__ __align__(16) bf16 lds_a[128*64];
  __shared__ __align__(16) bf16 lds_b[128*64];
  const int tid  = threadIdx.x;
  const int wave = tid >> 6;
  const int lane = tid & 63;
  const int wm = wave >> 1, wn = wave & 1;
  const int bm = blockIdx.y, bn = blockIdx.x;

  const int r_in = lane >> 3;             // row within 8-row chunk
  const int kc_l = lane & 7;              // 16B k-chunk this lane stages
  const size_t arow0 = (size_t)bm * 128;
  const size_t brow0 = (size_t)bn * 128;

  f32x4 acc[4][4];
#pragma unroll
  for (int i = 0; i < 4; ++i)
#pragma unroll
    for (int j = 0; j < 4; ++j) acc[i][j] = {0.f, 0.f, 0.f, 0.f};

  const int mrow = lane & 15;
  const int kg   = lane >> 4;

  for (int k0 = 0; k0 < K; k0 += 64) {
    __syncthreads();  // previous tile's LDS reads complete before restaging
#pragma unroll
    for (int iss = 0; iss < 4; ++iss) {
      const int chunk = iss * 4 + wave;        // 16 chunks of 8 rows
      const int row   = chunk * 8 + r_in;
      gl_lds16(A + (arow0 + row) * (size_t)K + (k0 + kc_l * 8), &lds_a[chunk * 512]);
      gl_lds16(W + (brow0 + row) * (size_t)K + (k0 + kc_l * 8), &lds_b[chunk * 512]);
    }
    __syncthreads();  // drains vmcnt(0) -> LDS valid
#pragma unroll
    for (int ks = 0; ks < 2; ++ks) {
      bf16x8 af[4], bfr[4];
#pragma unroll
      for (int t = 0; t < 4; ++t) {
        const int ra = wm * 64 + t * 16 + mrow;
        af[t] = *(const bf16x8*)&lds_a[(ra * 8 + ks * 4 + kg) * 8];
        const int rb = wn * 64 + t * 16 + mrow;
        bfr[t] = *(const bf16x8*)&lds_b[(rb * 8 + ks * 4 + kg) * 8];
      }
#pragma unroll
      for (int i = 0; i < 4; ++i)
#pragma unroll
        for (int j = 0; j < 4; ++j)
          acc[i][j] = __builtin_amdgcn_mfma_f32_16x16x32_bf16(af[i], bfr[j], acc[i][j], 0, 0, 0);
    }
  }

  // Epilogue. C/D layout: col = lane&15, row = (lane>>4)*4 + reg.
#pragma unroll
  for (int j = 0; j < 4; ++j) {
    const int col = bn * 128 + wn * 64 + j * 16 + mrow;
    float bv = 0.f;
    if constexpr (HAS_BIAS) bv = bias[col];
#pragma unroll
    for (int i = 0; i < 4; ++i) {
      const int row0 = bm * 128 + wm * 64 + i * 16 + kg * 4;
#pragma unroll
      for (int r = 0; r < 4; ++r) {
        const size_t off = (size_t)(row0 + r) * N + col;
        float v = acc[i][j][r] + bv;
        if constexpr (MODE == 0) {
          ((bf16*)outp)[off] = (bf16)v;
        } else if constexpr (MODE == 1) {
          ((float*)outp)[off] = v;
        } else if constexpr (MODE == 2) {
          ((bf16*)outp)[off] = (bf16)(v + ((const float*)extra)[off]);
        } else if constexpr (MODE == 3) {
          const float g = (float)((const bf16*)extra)[off];
          const float s = v / (1.f + expf(-v));
          ((bf16*)outp)[off] = (bf16)(g * s);
        } else if constexpr (MODE == 4) {
          ((float*)outp)[off] = v + (float)((const bf16*)extra)[off];
        } else if constexpr (MODE == 5) {
          const float sp = (v > 15.f) ? v : log1pf(expf(v));
          ((bf16*)outp)[off] = (bf16)sp;
        } else {  // MODE 6
          const float d = (float)((const bf16*)extra)[off];
          ((bf16*)outp)[off] = (bf16)(d * v);
        }
      }
    }
  }
}

// ===========================================================================
// depthwise conv1d(k=3, pad=1 along L, per-batch) + bias + silu. 8 d's/thread.
// ===========================================================================
__global__ void conv_silu_kernel(const bf16* __restrict__ t1, const float* __restrict__ cw,
                                 const float* __restrict__ cb, bf16* __restrict__ xc) {
  const int gid  = blockIdx.x * 256 + threadIdx.x;   // MT*DM/8 threads
  const int dgrp = gid & (DM / 8 - 1);
  const int bl   = gid >> 7;
  const int l    = bl & (SL - 1);
  const int d0   = dgrp * 8;
  const bf16* p  = t1 + (size_t)bl * DM + d0;
  bf16x8 cc = *(const bf16x8*)p;
  bf16x8 lf, rt;
#pragma unroll
  for (int j = 0; j < 8; ++j) { lf[j] = (bf16)0.f; rt[j] = (bf16)0.f; }
  if (l > 0)      lf = *(const bf16x8*)(p - DM);
  if (l < SL - 1) rt = *(const bf16x8*)(p + DM);
  bf16x8 o;
#pragma unroll
  for (int j = 0; j < 8; ++j) {
    const int d = d0 + j;
    float y = cw[d * 3 + 0] * (float)lf[j] + cw[d * 3 + 1] * (float)cc[j]
            + cw[d * 3 + 2] * (float)rt[j] + cb[d];
    y = y / (1.f + expf(-y));
    o[j] = (bf16)y;
  }
  *(bf16x8*)(xc + (size_t)bl * DM + d0) = o;
}

// ===========================================================================
// Parallel scan over L, 3 phases, chunked (LC=256, NC=16).
// h_l = sum_{i<=l} Bx_i * exp(-sum_{j<=i} nla_j).
// Phase 1: per (b,ch,chunk) thread — local lp-cumsum + local S; S_local
//          written in-place over nla (bf16); chunk totals (Lp,T) to ws.
//          Thread mapping: lanes adjacent in ch -> coalesced.
// Phase 2: per (b,ch) — 16-entry exclusive scan of totals in fp32 (exact).
// Phase 3: h = Soff + exp(-lpoff)*S_local, written over Bx.
// ===========================================================================
__global__ void scan_phase1(bf16* nla_sl, const bf16* __restrict__ bx,
                            float* __restrict__ Lp_tot, float* __restrict__ T_tot) {
  const int g  = blockIdx.x * 256 + threadIdx.x;   // 131072 threads
  const int ch = g & (DH - 1);
  const int rc = g >> 11;          // 0..63
  const int b  = rc & (NB - 1);
  const int c  = rc >> 2;          // 0..15
  const int bc = b * DH + ch;
  size_t off = ((size_t)(b * SL + c * LC)) * DH + ch;
  float lp = 0.f, S = 0.f;
#pragma unroll 8
  for (int l = 0; l < LC; ++l, off += DH) {
    const float a = (float)nla_sl[off];
    const float x = (float)bx[off];
    lp += a;
    const float e = __expf(-fminf(fmaxf(lp, -80.f), 80.f));
    S = fmaf(x, e, S);
    nla_sl[off] = (bf16)S;
  }
  Lp_tot[c * (NB * DH) + bc] = lp;
  T_tot [c * (NB * DH) + bc] = S;
}

__global__ void scan_phase2(const float* __restrict__ Lp_tot, const float* __restrict__ T_tot,
                            float* __restrict__ lpoff, float* __restrict__ Soff) {
  const int bc = blockIdx.x * 256 + threadIdx.x;   // 0..8191
  float lp = 0.f, S = 0.f;
#pragma unroll
  for (int c = 0; c < NC; ++c) {
    lpoff[c * (NB * DH) + bc] = lp;
    Soff [c * (NB * DH) + bc] = S;
    const float e = __expf(-fminf(fmaxf(lp, -80.f), 80.f));
    S  = fmaf(e, T_tot[c * (NB * DH) + bc], S);
    lp += Lp_tot[c * (NB * DH) + bc];
  }
}

__global__ void scan_phase3(const bf16* __restrict__ S_local, bf16* __restrict__ h,
                            const float* __restrict__ lpoff, const float* __restrict__ Soff) {
  const int g  = blockIdx.x * 256 + threadIdx.x;
  const int ch = g & (DH - 1);
  const int rc = g >> 11;
  const int b  = rc & (NB - 1);
  const int c  = rc >> 2;
  const int bc = b * DH + ch;
  const float lo = lpoff[c * (NB * DH) + bc];
  const float so = Soff [c * (NB * DH) + bc];
  const float es = __expf(-fminf(fmaxf(lo, -80.f), 80.f));
  size_t off = ((size_t)(b * SL + c * LC)) * DH + ch;
#pragma unroll 8
  for (int l = 0; l < LC; ++l, off += DH) {
    h[off] = (bf16)fmaf(es, (float)S_local[off], so);
  }
}

// ===========================================================================
// Workspace (max live 186 MB <= proven-safe 192 MB), offsets in MB:
//  [  0.. 24): bf16 weights (persistent): w1 0-2, w2 2-4, w3 4-6, D_w 6-8,
//              A_w 8-12, B_w 12-16, dl_w 16-20, C_w 20-24
//  [ 24.. 56): xc -> ssm
//  [ 56..120): t1/xbf (sub-ranges) -> dlo -> bxh (Bx, then h via phase3) ; z
//  [120..184): nla -> S_local (phase1, in-place) -> dtmp (fp32, D-GEMM)
//  [184..186): scan totals: Lp_tot, T_tot, lpoff, Soff (512 KB each)
// ===========================================================================
extern "C" void kernel_launch(void* const* d_in, const int* in_sizes, int n_in,
                              void* d_out, int out_size, void* d_ws, size_t ws_size,
                              hipStream_t stream) {
  const float* x    = (const float*)d_in[0];
  const float* w1   = (const float*)d_in[1];
  const float* w2   = (const float*)d_in[2];
  const float* w3   = (const float*)d_in[3];
  const float* cw   = (const float*)d_in[4];
  const float* cb   = (const float*)d_in[5];
  const float* A_w  = (const float*)d_in[6];
  const float* A_b  = (const float*)d_in[7];
  const float* B_w  = (const float*)d_in[8];
  const float* B_b  = (const float*)d_in[9];
  const float* C_w  = (const float*)d_in[10];
  const float* C_b  = (const float*)d_in[11];
  const float* D_w  = (const float*)d_in[12];
  const float* D_b  = (const float*)d_in[13];
  const float* dl_w = (const float*)d_in[14];
  const float* dl_b = (const float*)d_in[15];

  const size_t MB = 1048576u;
  char* ws = (char*)d_ws;
  bf16* w1b  = (bf16*)(ws + 0*MB);
  bf16* w2b  = (bf16*)(ws + 2*MB);
  bf16* w3b  = (bf16*)(ws + 4*MB);
  bf16* Dwb  = (bf16*)(ws + 6*MB);
  bf16* Awb  = (bf16*)(ws + 8*MB);
  bf16* Bwb  = (bf16*)(ws + 12*MB);
  bf16* dlwb = (bf16*)(ws + 16*MB);
  bf16* Cwb  = (bf16*)(ws + 20*MB);
  bf16* xc   = (bf16*)(ws + 24*MB);
  bf16* ssm  = xc;
  bf16* t1   = (bf16*)(ws + 56*MB);
  bf16* z    = t1;
  bf16* xbf  = (bf16*)(ws + 88*MB);
  bf16* dlo  = (bf16*)(ws + 56*MB);   // 64 MB region
  bf16* bxh  = dlo;                    // Bx, then h (phase3 writes)
  bf16* nla  = (bf16*)(ws + 120*MB);  // 64 MB; S_local in-place; then dtmp
  float* dtmp = (float*)nla;
  float* Lp_tot = (float*)(ws + 184*MB);
  float* T_tot  = (float*)(ws + 184*MB + 524288u);
  float* lpoff  = (float*)(ws + 185*MB);
  float* Soff   = (float*)(ws + 185*MB + 524288u);
  float* outp = (float*)d_out;

  dim3 blk(256);
  dim3 g1(DM / 128, MT / 128);   // N=1024
  dim3 g2(DH / 128, MT / 128);   // N=2048

  // --- convert inputs to bf16 (sanitizing) ---
  cvt_kernel<<<4096, blk, 0, stream>>>(x,    xbf,  MT*DM);
  cvt_kernel<<<512,  blk, 0, stream>>>(w1,   w1b,  DM*DM);
  cvt_kernel<<<512,  blk, 0, stream>>>(w2,   w2b,  DM*DM);
  cvt_kernel<<<512,  blk, 0, stream>>>(w3,   w3b,  DM*DM);
  cvt_kernel<<<512,  blk, 0, stream>>>(D_w,  Dwb,  DM*DM);
  cvt_kernel<<<1024, blk, 0, stream>>>(A_w,  Awb,  DH*DM);
  cvt_kernel<<<1024, blk, 0, stream>>>(B_w,  Bwb,  DH*DM);
  cvt_kernel<<<1024, blk, 0, stream>>>(dl_w, dlwb, DH*DM);
  cvt_kernel<<<1024, blk, 0, stream>>>(C_w,  Cwb,  DM*DH);

  // --- pipeline ---
  gemm_bt<0,false><<<g1, blk, 0, stream>>>(xbf, w1b,  nullptr, nullptr, t1,   MT, DM, DM);
  conv_silu_kernel<<<MT * DM / 8 / 256, blk, 0, stream>>>(t1, cw, cb, xc);
  gemm_bt<5,true ><<<g2, blk, 0, stream>>>(xc,  dlwb, dl_b,    nullptr, dlo,  MT, DH, DM);
  gemm_bt<6,true ><<<g2, blk, 0, stream>>>(xc,  Awb,  A_b,     dlo,     nla,  MT, DH, DM);
  gemm_bt<0,true ><<<g2, blk, 0, stream>>>(xc,  Bwb,  B_b,     nullptr, bxh,  MT, DH, DM);
  scan_phase1<<<MT * NC * DH / SL / 256, blk, 0, stream>>>(nla, bxh, Lp_tot, T_tot);
  scan_phase2<<<NB * DH / 256, blk, 0, stream>>>(Lp_tot, T_tot, lpoff, Soff);
  scan_phase3<<<MT * NC * DH / SL / 256, blk, 0, stream>>>(nla, bxh, lpoff, Soff);
  gemm_bt<1,true ><<<g1, blk, 0, stream>>>(xc,  Dwb,  D_b,     nullptr, dtmp, MT, DM, DM);
  gemm_bt<2,true ><<<g1, blk, 0, stream>>>(bxh, Cwb,  C_b,     dtmp,    ssm,  MT, DM, DH);
  gemm_bt<3,false><<<g1, blk, 0, stream>>>(ssm, w2b,  nullptr, ssm,     z,    MT, DM, DM);
  gemm_bt<4,false><<<g1, blk, 0, stream>>>(z,   w3b,  nullptr, ssm,     outp, MT, DM, DM);
}

// Round 7
// 992.583 us; speedup vs baseline: 1.4457x; 1.1095x over previous
//
#include <hip/hip_runtime.h>
#include <hip/hip_bf16.h>
#include <stdint.h>
#include <math.h>

#define DM 1024
#define DH 2048
#define NB 4
#define SL 4096
#define MT (NB*SL)   // 16384 rows
#define LC 256       // scan chunk length
#define NC (SL/LC)   // 16 chunks per channel

typedef __bf16 bf16;
typedef __attribute__((ext_vector_type(8))) __bf16 bf16x8;
typedef __attribute__((ext_vector_type(4))) float f32x4;

// ---- async global->LDS, 16B per lane. LDS dest = wave-uniform base + lane*16.
__device__ __forceinline__ void gl_lds16(const bf16* g, bf16* l) {
  typedef __attribute__((address_space(1))) uint32_t* gp_t;
  typedef __attribute__((address_space(3))) uint32_t* lp_t;
  gp_t gp = (gp_t)(uintptr_t)g;
  lp_t lp = (lp_t)(uint32_t)(uintptr_t)l;
  __builtin_amdgcn_global_load_lds(gp, lp, 16, 0, 0);
}

// ===========================================================================
// fp32 -> bf16 sanitizing convert (NaN -> 0, clamp +-65504). Grid-stride.
// ===========================================================================
__global__ void cvt_kernel(const float* __restrict__ in, bf16* __restrict__ out, int n) {
  for (int i = blockIdx.x * 256 + threadIdx.x; i < n; i += gridDim.x * 256) {
    float v = in[i];
    v = (v == v) ? fminf(fmaxf(v, -65504.f), 65504.f) : 0.f;
    out[i] = (bf16)v;
  }
}

// ===========================================================================
// GEMM: out[M,N] = A[M,K] @ W[N,K]^T (+bias) with fused epilogues.
// A, W bf16 (pre-converted); bias fp32.
// 128x128 tile, BK=64, 4 waves (2x2 of 64x64), mfma_f32_16x16x32_bf16.
// Staging: async global_load_lds width=16.
// LDS layout XOR-swizzled to kill 16-way ds_read_b128 bank conflicts:
//   lane l = r*8+c fetches global k-chunk (c^r); slot(row,kc) = row*8 + (kc^(row&7)).
//   Round-trip: slot content = k-chunk (c^r) at slot c -> read kc at slot kc^r.  ✓
//   Read banks: lanes 0..15, rows t*16+0..15, bank = 4*((kc^(row&7))) + i -> all 32.
// MODE 0: out_bf16 = acc (+bias)
// MODE 1: out_f32  = acc + bias
// MODE 2: out_bf16 = acc + bias + extra_f32[off]
// MODE 3: out_bf16 = extra_bf16[off] * silu(acc)            (z-gate)
// MODE 4: out_f32  = acc + extra_bf16[off]                  (residual, final)
// MODE 5: out_bf16 = softplus(acc + bias)                   (delta)
// MODE 6: out_bf16 = extra_bf16[off] * (acc + bias)         (nla = delta*A_t)
// ===========================================================================
template<int MODE, bool HAS_BIAS>
__global__ __launch_bounds__(256, 3)
void gemm_bt(const bf16* __restrict__ A, const bf16* __restrict__ W,
             const float* __restrict__ bias, const void* __restrict__ extra,
             void* __restrict__ outp, int M, int N, int K) {
  __shared__ __align__(16) bf16 lds_a[128*64];
  __shared__ __align__(16) bf16 lds_b[128*64];
  const int tid  = threadIdx.x;
  const int wave = tid >> 6;
  const int lane = tid & 63;
  const int wm = wave >> 1, wn = wave & 1;
  const int bm = blockIdx.y, bn = blockIdx.x;

  const int r_in = lane >> 3;             // row within 8-row chunk
  const int kc_l = (lane & 7) ^ r_in;     // swizzle: this lane fetches k-chunk c^r
  const size_t arow0 = (size_t)bm * 128;
  const size_t brow0 = (size_t)bn * 128;

  f32x4 acc[4][4];
#pragma unroll
  for (int i = 0; i < 4; ++i)
#pragma unroll
    for (int j = 0; j < 4; ++j) acc[i][j] = {0.f, 0.f, 0.f, 0.f};

  const int mrow = lane & 15;
  const int kg   = lane >> 4;

  for (int k0 = 0; k0 < K; k0 += 64) {
    __syncthreads();  // previous tile's LDS reads complete before restaging
#pragma unroll
    for (int iss = 0; iss < 4; ++iss) {
      const int chunk = iss * 4 + wave;        // 16 chunks of 8 rows
      const int row   = chunk * 8 + r_in;
      gl_lds16(A + (arow0 + row) * (size_t)K + (k0 + kc_l * 8), &lds_a[chunk * 512]);
      gl_lds16(W + (brow0 + row) * (size_t)K + (k0 + kc_l * 8), &lds_b[chunk * 512]);
    }
    __syncthreads();  // drains vmcnt(0) -> LDS valid
#pragma unroll
    for (int ks = 0; ks < 2; ++ks) {
      bf16x8 af[4], bfr[4];
#pragma unroll
      for (int t = 0; t < 4; ++t) {
        const int ra = wm * 64 + t * 16 + mrow;
        const int sa = ra * 8 + ((ks * 4 + kg) ^ (ra & 7));
        af[t] = *(const bf16x8*)&lds_a[sa * 8];
        const int rb = wn * 64 + t * 16 + mrow;
        const int sb = rb * 8 + ((ks * 4 + kg) ^ (rb & 7));
        bfr[t] = *(const bf16x8*)&lds_b[sb * 8];
      }
#pragma unroll
      for (int i = 0; i < 4; ++i)
#pragma unroll
        for (int j = 0; j < 4; ++j)
          acc[i][j] = __builtin_amdgcn_mfma_f32_16x16x32_bf16(af[i], bfr[j], acc[i][j], 0, 0, 0);
    }
  }

  // Epilogue. C/D layout: col = lane&15, row = (lane>>4)*4 + reg.
#pragma unroll
  for (int j = 0; j < 4; ++j) {
    const int col = bn * 128 + wn * 64 + j * 16 + mrow;
    float bv = 0.f;
    if constexpr (HAS_BIAS) bv = bias[col];
#pragma unroll
    for (int i = 0; i < 4; ++i) {
      const int row0 = bm * 128 + wm * 64 + i * 16 + kg * 4;
#pragma unroll
      for (int r = 0; r < 4; ++r) {
        const size_t off = (size_t)(row0 + r) * N + col;
        float v = acc[i][j][r] + bv;
        if constexpr (MODE == 0) {
          ((bf16*)outp)[off] = (bf16)v;
        } else if constexpr (MODE == 1) {
          ((float*)outp)[off] = v;
        } else if constexpr (MODE == 2) {
          ((bf16*)outp)[off] = (bf16)(v + ((const float*)extra)[off]);
        } else if constexpr (MODE == 3) {
          const float g = (float)((const bf16*)extra)[off];
          const float s = v / (1.f + expf(-v));
          ((bf16*)outp)[off] = (bf16)(g * s);
        } else if constexpr (MODE == 4) {
          ((float*)outp)[off] = v + (float)((const bf16*)extra)[off];
        } else if constexpr (MODE == 5) {
          const float sp = (v > 15.f) ? v : log1pf(expf(v));
          ((bf16*)outp)[off] = (bf16)sp;
        } else {  // MODE 6
          const float d = (float)((const bf16*)extra)[off];
          ((bf16*)outp)[off] = (bf16)(d * v);
        }
      }
    }
  }
}

// ===========================================================================
// depthwise conv1d(k=3, pad=1 along L, per-batch) + bias + silu. 8 d's/thread.
// ===========================================================================
__global__ void conv_silu_kernel(const bf16* __restrict__ t1, const float* __restrict__ cw,
                                 const float* __restrict__ cb, bf16* __restrict__ xc) {
  const int gid  = blockIdx.x * 256 + threadIdx.x;   // MT*DM/8 threads
  const int dgrp = gid & (DM / 8 - 1);
  const int bl   = gid >> 7;
  const int l    = bl & (SL - 1);
  const int d0   = dgrp * 8;
  const bf16* p  = t1 + (size_t)bl * DM + d0;
  bf16x8 cc = *(const bf16x8*)p;
  bf16x8 lf, rt;
#pragma unroll
  for (int j = 0; j < 8; ++j) { lf[j] = (bf16)0.f; rt[j] = (bf16)0.f; }
  if (l > 0)      lf = *(const bf16x8*)(p - DM);
  if (l < SL - 1) rt = *(const bf16x8*)(p + DM);
  bf16x8 o;
#pragma unroll
  for (int j = 0; j < 8; ++j) {
    const int d = d0 + j;
    float y = cw[d * 3 + 0] * (float)lf[j] + cw[d * 3 + 1] * (float)cc[j]
            + cw[d * 3 + 2] * (float)rt[j] + cb[d];
    y = y / (1.f + expf(-y));
    o[j] = (bf16)y;
  }
  *(bf16x8*)(xc + (size_t)bl * DM + d0) = o;
}

// ===========================================================================
// Parallel scan over L, 3 phases, chunked (LC=256, NC=16).
// h_l = sum_{i<=l} Bx_i * exp(-sum_{j<=i} nla_j).
// ===========================================================================
__global__ void scan_phase1(bf16* nla_sl, const bf16* __restrict__ bx,
                            float* __restrict__ Lp_tot, float* __restrict__ T_tot) {
  const int g  = blockIdx.x * 256 + threadIdx.x;   // 131072 threads
  const int ch = g & (DH - 1);
  const int rc = g >> 11;          // 0..63
  const int b  = rc & (NB - 1);
  const int c  = rc >> 2;          // 0..15
  const int bc = b * DH + ch;
  size_t off = ((size_t)(b * SL + c * LC)) * DH + ch;
  float lp = 0.f, S = 0.f;
#pragma unroll 8
  for (int l = 0; l < LC; ++l, off += DH) {
    const float a = (float)nla_sl[off];
    const float x = (float)bx[off];
    lp += a;
    const float e = __expf(-fminf(fmaxf(lp, -80.f), 80.f));
    S = fmaf(x, e, S);
    nla_sl[off] = (bf16)S;
  }
  Lp_tot[c * (NB * DH) + bc] = lp;
  T_tot [c * (NB * DH) + bc] = S;
}

__global__ void scan_phase2(const float* __restrict__ Lp_tot, const float* __restrict__ T_tot,
                            float* __restrict__ lpoff, float* __restrict__ Soff) {
  const int bc = blockIdx.x * 256 + threadIdx.x;   // 0..8191
  float lp = 0.f, S = 0.f;
#pragma unroll
  for (int c = 0; c < NC; ++c) {
    lpoff[c * (NB * DH) + bc] = lp;
    Soff [c * (NB * DH) + bc] = S;
    const float e = __expf(-fminf(fmaxf(lp, -80.f), 80.f));
    S  = fmaf(e, T_tot[c * (NB * DH) + bc], S);
    lp += Lp_tot[c * (NB * DH) + bc];
  }
}

__global__ void scan_phase3(const bf16* __restrict__ S_local, bf16* __restrict__ h,
                            const float* __restrict__ lpoff, const float* __restrict__ Soff) {
  const int g  = blockIdx.x * 256 + threadIdx.x;
  const int ch = g & (DH - 1);
  const int rc = g >> 11;
  const int b  = rc & (NB - 1);
  const int c  = rc >> 2;
  const int bc = b * DH + ch;
  const float lo = lpoff[c * (NB * DH) + bc];
  const float so = Soff [c * (NB * DH) + bc];
  const float es = __expf(-fminf(fmaxf(lo, -80.f), 80.f));
  size_t off = ((size_t)(b * SL + c * LC)) * DH + ch;
#pragma unroll 8
  for (int l = 0; l < LC; ++l, off += DH) {
    h[off] = (bf16)fmaf(es, (float)S_local[off], so);
  }
}

// ===========================================================================
// Workspace (max live 186 MB <= proven-safe 192 MB), offsets in MB:
//  [  0.. 24): bf16 weights (persistent)
//  [ 24.. 56): xc -> ssm
//  [ 56..120): t1/xbf -> dlo -> bxh (Bx, then h) ; z
//  [120..184): nla -> S_local (in-place) -> dtmp (fp32)
//  [184..186): scan totals
// ===========================================================================
extern "C" void kernel_launch(void* const* d_in, const int* in_sizes, int n_in,
                              void* d_out, int out_size, void* d_ws, size_t ws_size,
                              hipStream_t stream) {
  const float* x    = (const float*)d_in[0];
  const float* w1   = (const float*)d_in[1];
  const float* w2   = (const float*)d_in[2];
  const float* w3   = (const float*)d_in[3];
  const float* cw   = (const float*)d_in[4];
  const float* cb   = (const float*)d_in[5];
  const float* A_w  = (const float*)d_in[6];
  const float* A_b  = (const float*)d_in[7];
  const float* B_w  = (const float*)d_in[8];
  const float* B_b  = (const float*)d_in[9];
  const float* C_w  = (const float*)d_in[10];
  const float* C_b  = (const float*)d_in[11];
  const float* D_w  = (const float*)d_in[12];
  const float* D_b  = (const float*)d_in[13];
  const float* dl_w = (const float*)d_in[14];
  const float* dl_b = (const float*)d_in[15];

  const size_t MB = 1048576u;
  char* ws = (char*)d_ws;
  bf16* w1b  = (bf16*)(ws + 0*MB);
  bf16* w2b  = (bf16*)(ws + 2*MB);
  bf16* w3b  = (bf16*)(ws + 4*MB);
  bf16* Dwb  = (bf16*)(ws + 6*MB);
  bf16* Awb  = (bf16*)(ws + 8*MB);
  bf16* Bwb  = (bf16*)(ws + 12*MB);
  bf16* dlwb = (bf16*)(ws + 16*MB);
  bf16* Cwb  = (bf16*)(ws + 20*MB);
  bf16* xc   = (bf16*)(ws + 24*MB);
  bf16* ssm  = xc;
  bf16* t1   = (bf16*)(ws + 56*MB);
  bf16* z    = t1;
  bf16* xbf  = (bf16*)(ws + 88*MB);
  bf16* dlo  = (bf16*)(ws + 56*MB);   // 64 MB region
  bf16* bxh  = dlo;                    // Bx, then h (phase3 writes)
  bf16* nla  = (bf16*)(ws + 120*MB);  // 64 MB; S_local in-place; then dtmp
  float* dtmp = (float*)nla;
  float* Lp_tot = (float*)(ws + 184*MB);
  float* T_tot  = (float*)(ws + 184*MB + 524288u);
  float* lpoff  = (float*)(ws + 185*MB);
  float* Soff   = (float*)(ws + 185*MB + 524288u);
  float* outp = (float*)d_out;

  dim3 blk(256);
  dim3 g1(DM / 128, MT / 128);   // N=1024
  dim3 g2(DH / 128, MT / 128);   // N=2048

  // --- convert inputs to bf16 (sanitizing) ---
  cvt_kernel<<<4096, blk, 0, stream>>>(x,    xbf,  MT*DM);
  cvt_kernel<<<512,  blk, 0, stream>>>(w1,   w1b,  DM*DM);
  cvt_kernel<<<512,  blk, 0, stream>>>(w2,   w2b,  DM*DM);
  cvt_kernel<<<512,  blk, 0, stream>>>(w3,   w3b,  DM*DM);
  cvt_kernel<<<512,  blk, 0, stream>>>(D_w,  Dwb,  DM*DM);
  cvt_kernel<<<1024, blk, 0, stream>>>(A_w,  Awb,  DH*DM);
  cvt_kernel<<<1024, blk, 0, stream>>>(B_w,  Bwb,  DH*DM);
  cvt_kernel<<<1024, blk, 0, stream>>>(dl_w, dlwb, DH*DM);
  cvt_kernel<<<1024, blk, 0, stream>>>(C_w,  Cwb,  DM*DH);

  // --- pipeline ---
  gemm_bt<0,false><<<g1, blk, 0, stream>>>(xbf, w1b,  nullptr, nullptr, t1,   MT, DM, DM);
  conv_silu_kernel<<<MT * DM / 8 / 256, blk, 0, stream>>>(t1, cw, cb, xc);
  gemm_bt<5,true ><<<g2, blk, 0, stream>>>(xc,  dlwb, dl_b,    nullptr, dlo,  MT, DH, DM);
  gemm_bt<6,true ><<<g2, blk, 0, stream>>>(xc,  Awb,  A_b,     dlo,     nla,  MT, DH, DM);
  gemm_bt<0,true ><<<g2, blk, 0, stream>>>(xc,  Bwb,  B_b,     nullptr, bxh,  MT, DH, DM);
  scan_phase1<<<MT * NC * DH / SL / 256, blk, 0, stream>>>(nla, bxh, Lp_tot, T_tot);
  scan_phase2<<<NB * DH / 256, blk, 0, stream>>>(Lp_tot, T_tot, lpoff, Soff);
  scan_phase3<<<MT * NC * DH / SL / 256, blk, 0, stream>>>(nla, bxh, lpoff, Soff);
  gemm_bt<1,true ><<<g1, blk, 0, stream>>>(xc,  Dwb,  D_b,     nullptr, dtmp, MT, DM, DM);
  gemm_bt<2,true ><<<g1, blk, 0, stream>>>(bxh, Cwb,  C_b,     dtmp,    ssm,  MT, DM, DH);
  gemm_bt<3,false><<<g1, blk, 0, stream>>>(ssm, w2b,  nullptr, ssm,     z,    MT, DM, DM);
  gemm_bt<4,false><<<g1, blk, 0, stream>>>(z,   w3b,  nullptr, ssm,     outp, MT, DM, DM);
}

// Round 8
// 989.886 us; speedup vs baseline: 1.4496x; 1.0027x over previous
//
#include <hip/hip_runtime.h>
#include <hip/hip_bf16.h>
#include <stdint.h>
#include <math.h>

#define DM 1024
#define DH 2048
#define NB 4
#define SL 4096
#define MT (NB*SL)   // 16384 rows
#define LC 256       // scan chunk length
#define NC (SL/LC)   // 16 chunks per channel

typedef __bf16 bf16;
typedef __attribute__((ext_vector_type(8))) __bf16 bf16x8;
typedef __attribute__((ext_vector_type(4))) float f32x4;

// ---- async global->LDS, 16B per lane. LDS dest = wave-uniform base + lane*16.
__device__ __forceinline__ void gl_lds16(const bf16* g, bf16* l) {
  typedef __attribute__((address_space(1))) uint32_t* gp_t;
  typedef __attribute__((address_space(3))) uint32_t* lp_t;
  gp_t gp = (gp_t)(uintptr_t)g;
  lp_t lp = (lp_t)(uint32_t)(uintptr_t)l;
  __builtin_amdgcn_global_load_lds(gp, lp, 16, 0, 0);
}

// ===========================================================================
// fp32 -> bf16 sanitizing convert (NaN -> 0, clamp +-65504). Grid-stride.
// ===========================================================================
__global__ void cvt_kernel(const float* __restrict__ in, bf16* __restrict__ out, int n) {
  for (int i = blockIdx.x * 256 + threadIdx.x; i < n; i += gridDim.x * 256) {
    float v = in[i];
    v = (v == v) ? fminf(fmaxf(v, -65504.f), 65504.f) : 0.f;
    out[i] = (bf16)v;
  }
}

// ===========================================================================
// GEMM: out[M,N] = A[M,K] @ W[N,K]^T (+bias), fused epilogues.
// N, K are COMPILE-TIME template params: staging addresses strength-reduce
// to pointer increments (round-6 PMC showed VALUBusy 81% from runtime-K
// address math: ~130 VALU ops/K-iter vs 77 cyc MFMA).
// 128x128 tile, BK=64, 4 waves (2x2 of 64x64), mfma_f32_16x16x32_bf16.
// Staging: async global_load_lds width=16; XOR-swizzled LDS (conflict-free,
// round-6 PMC: SQ_LDS_BANK_CONFLICT = 0).
// MODE 0: out_bf16 = acc (+bias)
// MODE 1: out_f32  = acc + bias
// MODE 2: out_bf16 = acc + bias + extra_f32[off]
// MODE 3: out_bf16 = extra_bf16[off] * silu(acc)            (z-gate)
// MODE 4: out_f32  = acc + extra_bf16[off]                  (residual, final)
// MODE 5: out_bf16 = softplus(acc + bias)                   (delta)
// MODE 6: out_bf16 = extra_bf16[off] * (acc + bias)         (nla = delta*A_t)
// ===========================================================================
template<int MODE, bool HAS_BIAS, int N, int K>
__global__ __launch_bounds__(256, 3)
void gemm_bt(const bf16* __restrict__ A, const bf16* __restrict__ W,
             const float* __restrict__ bias, const void* __restrict__ extra,
             void* __restrict__ outp) {
  __shared__ __align__(16) bf16 lds_a[128*64];
  __shared__ __align__(16) bf16 lds_b[128*64];
  const int tid  = threadIdx.x;
  const int wave = tid >> 6;
  const int lane = tid & 63;
  const int wm = wave >> 1, wn = wave & 1;
  const int bm = blockIdx.y, bn = blockIdx.x;

  const int r_in = lane >> 3;             // row within 8-row chunk
  const int kc_l = (lane & 7) ^ r_in;     // swizzle: this lane fetches k-chunk c^r
  const size_t arow0 = (size_t)bm * 128;
  const size_t brow0 = (size_t)bn * 128;

  f32x4 acc[4][4];
#pragma unroll
  for (int i = 0; i < 4; ++i)
#pragma unroll
    for (int j = 0; j < 4; ++j) acc[i][j] = {0.f, 0.f, 0.f, 0.f};

  const int mrow = lane & 15;
  const int kg   = lane >> 4;

  // Per-lane staging pointers, advanced by 64 elems per K-iter (strength-
  // reduced; K is a compile-time constant).
  const bf16* pa[4];
  const bf16* pb[4];
#pragma unroll
  for (int iss = 0; iss < 4; ++iss) {
    const int chunk = iss * 4 + wave;
    const int row   = chunk * 8 + r_in;
    pa[iss] = A + (arow0 + row) * (size_t)K + kc_l * 8;
    pb[iss] = W + (brow0 + row) * (size_t)K + kc_l * 8;
  }

#pragma unroll 1
  for (int k0 = 0; k0 < K; k0 += 64) {
    __syncthreads();  // previous tile's LDS reads complete before restaging
#pragma unroll
    for (int iss = 0; iss < 4; ++iss) {
      const int chunk = iss * 4 + wave;
      gl_lds16(pa[iss], &lds_a[chunk * 512]);
      gl_lds16(pb[iss], &lds_b[chunk * 512]);
      pa[iss] += 64;
      pb[iss] += 64;
    }
    __syncthreads();  // drains vmcnt(0) -> LDS valid
#pragma unroll
    for (int ks = 0; ks < 2; ++ks) {
      bf16x8 af[4], bfr[4];
#pragma unroll
      for (int t = 0; t < 4; ++t) {
        const int ra = wm * 64 + t * 16 + mrow;
        const int sa = ra * 8 + ((ks * 4 + kg) ^ (ra & 7));
        af[t] = *(const bf16x8*)&lds_a[sa * 8];
        const int rb = wn * 64 + t * 16 + mrow;
        const int sb = rb * 8 + ((ks * 4 + kg) ^ (rb & 7));
        bfr[t] = *(const bf16x8*)&lds_b[sb * 8];
      }
#pragma unroll
      for (int i = 0; i < 4; ++i)
#pragma unroll
        for (int j = 0; j < 4; ++j)
          acc[i][j] = __builtin_amdgcn_mfma_f32_16x16x32_bf16(af[i], bfr[j], acc[i][j], 0, 0, 0);
    }
  }

  // Epilogue. C/D layout: col = lane&15, row = (lane>>4)*4 + reg.
#pragma unroll
  for (int j = 0; j < 4; ++j) {
    const int col = bn * 128 + wn * 64 + j * 16 + mrow;
    float bv = 0.f;
    if constexpr (HAS_BIAS) bv = bias[col];
#pragma unroll
    for (int i = 0; i < 4; ++i) {
      const int row0 = bm * 128 + wm * 64 + i * 16 + kg * 4;
#pragma unroll
      for (int r = 0; r < 4; ++r) {
        const size_t off = (size_t)(row0 + r) * N + col;
        float v = acc[i][j][r] + bv;
        if constexpr (MODE == 0) {
          ((bf16*)outp)[off] = (bf16)v;
        } else if constexpr (MODE == 1) {
          ((float*)outp)[off] = v;
        } else if constexpr (MODE == 2) {
          ((bf16*)outp)[off] = (bf16)(v + ((const float*)extra)[off]);
        } else if constexpr (MODE == 3) {
          const float g = (float)((const bf16*)extra)[off];
          const float s = v / (1.f + expf(-v));
          ((bf16*)outp)[off] = (bf16)(g * s);
        } else if constexpr (MODE == 4) {
          ((float*)outp)[off] = v + (float)((const bf16*)extra)[off];
        } else if constexpr (MODE == 5) {
          const float sp = (v > 15.f) ? v : log1pf(expf(v));
          ((bf16*)outp)[off] = (bf16)sp;
        } else {  // MODE 6
          const float d = (float)((const bf16*)extra)[off];
          ((bf16*)outp)[off] = (bf16)(d * v);
        }
      }
    }
  }
}

// ===========================================================================
// depthwise conv1d(k=3, pad=1 along L, per-batch) + bias + silu. 8 d's/thread.
// ===========================================================================
__global__ void conv_silu_kernel(const bf16* __restrict__ t1, const float* __restrict__ cw,
                                 const float* __restrict__ cb, bf16* __restrict__ xc) {
  const int gid  = blockIdx.x * 256 + threadIdx.x;   // MT*DM/8 threads
  const int dgrp = gid & (DM / 8 - 1);
  const int bl   = gid >> 7;
  const int l    = bl & (SL - 1);
  const int d0   = dgrp * 8;
  const bf16* p  = t1 + (size_t)bl * DM + d0;
  bf16x8 cc = *(const bf16x8*)p;
  bf16x8 lf, rt;
#pragma unroll
  for (int j = 0; j < 8; ++j) { lf[j] = (bf16)0.f; rt[j] = (bf16)0.f; }
  if (l > 0)      lf = *(const bf16x8*)(p - DM);
  if (l < SL - 1) rt = *(const bf16x8*)(p + DM);
  bf16x8 o;
#pragma unroll
  for (int j = 0; j < 8; ++j) {
    const int d = d0 + j;
    float y = cw[d * 3 + 0] * (float)lf[j] + cw[d * 3 + 1] * (float)cc[j]
            + cw[d * 3 + 2] * (float)rt[j] + cb[d];
    y = y / (1.f + expf(-y));
    o[j] = (bf16)y;
  }
  *(bf16x8*)(xc + (size_t)bl * DM + d0) = o;
}

// ===========================================================================
// Parallel scan over L, 3 phases, chunked (LC=256, NC=16).
// h_l = sum_{i<=l} Bx_i * exp(-sum_{j<=i} nla_j).
// ===========================================================================
__global__ void scan_phase1(bf16* nla_sl, const bf16* __restrict__ bx,
                            float* __restrict__ Lp_tot, float* __restrict__ T_tot) {
  const int g  = blockIdx.x * 256 + threadIdx.x;   // 131072 threads
  const int ch = g & (DH - 1);
  const int rc = g >> 11;          // 0..63
  const int b  = rc & (NB - 1);
  const int c  = rc >> 2;          // 0..15
  const int bc = b * DH + ch;
  size_t off = ((size_t)(b * SL + c * LC)) * DH + ch;
  float lp = 0.f, S = 0.f;
#pragma unroll 8
  for (int l = 0; l < LC; ++l, off += DH) {
    const float a = (float)nla_sl[off];
    const float x = (float)bx[off];
    lp += a;
    const float e = __expf(-fminf(fmaxf(lp, -80.f), 80.f));
    S = fmaf(x, e, S);
    nla_sl[off] = (bf16)S;
  }
  Lp_tot[c * (NB * DH) + bc] = lp;
  T_tot [c * (NB * DH) + bc] = S;
}

__global__ void scan_phase2(const float* __restrict__ Lp_tot, const float* __restrict__ T_tot,
                            float* __restrict__ lpoff, float* __restrict__ Soff) {
  const int bc = blockIdx.x * 256 + threadIdx.x;   // 0..8191
  float lp = 0.f, S = 0.f;
#pragma unroll
  for (int c = 0; c < NC; ++c) {
    lpoff[c * (NB * DH) + bc] = lp;
    Soff [c * (NB * DH) + bc] = S;
    const float e = __expf(-fminf(fmaxf(lp, -80.f), 80.f));
    S  = fmaf(e, T_tot[c * (NB * DH) + bc], S);
    lp += Lp_tot[c * (NB * DH) + bc];
  }
}

__global__ void scan_phase3(const bf16* __restrict__ S_local, bf16* __restrict__ h,
                            const float* __restrict__ lpoff, const float* __restrict__ Soff) {
  const int g  = blockIdx.x * 256 + threadIdx.x;
  const int ch = g & (DH - 1);
  const int rc = g >> 11;
  const int b  = rc & (NB - 1);
  const int c  = rc >> 2;
  const int bc = b * DH + ch;
  const float lo = lpoff[c * (NB * DH) + bc];
  const float so = Soff [c * (NB * DH) + bc];
  const float es = __expf(-fminf(fmaxf(lo, -80.f), 80.f));
  size_t off = ((size_t)(b * SL + c * LC)) * DH + ch;
#pragma unroll 8
  for (int l = 0; l < LC; ++l, off += DH) {
    h[off] = (bf16)fmaf(es, (float)S_local[off], so);
  }
}

// ===========================================================================
// Workspace (max live 186 MB <= proven-safe 192 MB), offsets in MB:
//  [  0.. 24): bf16 weights (persistent)
//  [ 24.. 56): xc -> ssm
//  [ 56..120): t1/xbf -> dlo -> bxh (Bx, then h) ; z
//  [120..184): nla -> S_local (in-place) -> dtmp (fp32)
//  [184..186): scan totals
// ===========================================================================
extern "C" void kernel_launch(void* const* d_in, const int* in_sizes, int n_in,
                              void* d_out, int out_size, void* d_ws, size_t ws_size,
                              hipStream_t stream) {
  const float* x    = (const float*)d_in[0];
  const float* w1   = (const float*)d_in[1];
  const float* w2   = (const float*)d_in[2];
  const float* w3   = (const float*)d_in[3];
  const float* cw   = (const float*)d_in[4];
  const float* cb   = (const float*)d_in[5];
  const float* A_w  = (const float*)d_in[6];
  const float* A_b  = (const float*)d_in[7];
  const float* B_w  = (const float*)d_in[8];
  const float* B_b  = (const float*)d_in[9];
  const float* C_w  = (const float*)d_in[10];
  const float* C_b  = (const float*)d_in[11];
  const float* D_w  = (const float*)d_in[12];
  const float* D_b  = (const float*)d_in[13];
  const float* dl_w = (const float*)d_in[14];
  const float* dl_b = (const float*)d_in[15];

  const size_t MB = 1048576u;
  char* ws = (char*)d_ws;
  bf16* w1b  = (bf16*)(ws + 0*MB);
  bf16* w2b  = (bf16*)(ws + 2*MB);
  bf16* w3b  = (bf16*)(ws + 4*MB);
  bf16* Dwb  = (bf16*)(ws + 6*MB);
  bf16* Awb  = (bf16*)(ws + 8*MB);
  bf16* Bwb  = (bf16*)(ws + 12*MB);
  bf16* dlwb = (bf16*)(ws + 16*MB);
  bf16* Cwb  = (bf16*)(ws + 20*MB);
  bf16* xc   = (bf16*)(ws + 24*MB);
  bf16* ssm  = xc;
  bf16* t1   = (bf16*)(ws + 56*MB);
  bf16* z    = t1;
  bf16* xbf  = (bf16*)(ws + 88*MB);
  bf16* dlo  = (bf16*)(ws + 56*MB);   // 64 MB region
  bf16* bxh  = dlo;                    // Bx, then h (phase3 writes)
  bf16* nla  = (bf16*)(ws + 120*MB);  // 64 MB; S_local in-place; then dtmp
  float* dtmp = (float*)nla;
  float* Lp_tot = (float*)(ws + 184*MB);
  float* T_tot  = (float*)(ws + 184*MB + 524288u);
  float* lpoff  = (float*)(ws + 185*MB);
  float* Soff   = (float*)(ws + 185*MB + 524288u);
  float* outp = (float*)d_out;

  dim3 blk(256);
  dim3 g1(DM / 128, MT / 128);   // N=1024
  dim3 g2(DH / 128, MT / 128);   // N=2048

  // --- convert inputs to bf16 (sanitizing) ---
  cvt_kernel<<<4096, blk, 0, stream>>>(x,    xbf,  MT*DM);
  cvt_kernel<<<512,  blk, 0, stream>>>(w1,   w1b,  DM*DM);
  cvt_kernel<<<512,  blk, 0, stream>>>(w2,   w2b,  DM*DM);
  cvt_kernel<<<512,  blk, 0, stream>>>(w3,   w3b,  DM*DM);
  cvt_kernel<<<512,  blk, 0, stream>>>(D_w,  Dwb,  DM*DM);
  cvt_kernel<<<1024, blk, 0, stream>>>(A_w,  Awb,  DH*DM);
  cvt_kernel<<<1024, blk, 0, stream>>>(B_w,  Bwb,  DH*DM);
  cvt_kernel<<<1024, blk, 0, stream>>>(dl_w, dlwb, DH*DM);
  cvt_kernel<<<1024, blk, 0, stream>>>(C_w,  Cwb,  DM*DH);

  // --- pipeline ---
  gemm_bt<0,false,DM,DM><<<g1, blk, 0, stream>>>(xbf, w1b,  nullptr, nullptr, t1);
  conv_silu_kernel<<<MT * DM / 8 / 256, blk, 0, stream>>>(t1, cw, cb, xc);
  gemm_bt<5,true ,DH,DM><<<g2, blk, 0, stream>>>(xc,  dlwb, dl_b,    nullptr, dlo);
  gemm_bt<6,true ,DH,DM><<<g2, blk, 0, stream>>>(xc,  Awb,  A_b,     dlo,     nla);
  gemm_bt<0,true ,DH,DM><<<g2, blk, 0, stream>>>(xc,  Bwb,  B_b,     nullptr, bxh);
  scan_phase1<<<MT * NC * DH / SL / 256, blk, 0, stream>>>(nla, bxh, Lp_tot, T_tot);
  scan_phase2<<<NB * DH / 256, blk, 0, stream>>>(Lp_tot, T_tot, lpoff, Soff);
  scan_phase3<<<MT * NC * DH / SL / 256, blk, 0, stream>>>(nla, bxh, lpoff, Soff);
  gemm_bt<1,true ,DM,DM><<<g1, blk, 0, stream>>>(xc,  Dwb,  D_b,     nullptr, dtmp);
  gemm_bt<2,true ,DM,DH><<<g1, blk, 0, stream>>>(bxh, Cwb,  C_b,     dtmp,    ssm);
  gemm_bt<3,false,DM,DM><<<g1, blk, 0, stream>>>(ssm, w2b,  nullptr, ssm,     z);
  gemm_bt<4,false,DM,DM><<<g1, blk, 0, stream>>>(z,   w3b,  nullptr, ssm,     outp);
}

// Round 9
// 872.728 us; speedup vs baseline: 1.6442x; 1.1342x over previous
//
#include <hip/hip_runtime.h>
#include <hip/hip_bf16.h>
#include <stdint.h>
#include <math.h>

#define DM 1024
#define DH 2048
#define NB 4
#define SL 4096
#define MT (NB*SL)   // 16384 rows
#define LC 256       // scan chunk length
#define NC (SL/LC)   // 16 chunks per channel

typedef __bf16 bf16;
typedef __attribute__((ext_vector_type(8))) __bf16 bf16x8;
typedef __attribute__((ext_vector_type(4))) float f32x4;

// ===========================================================================
// fp32 -> bf16 sanitizing convert (NaN -> 0, clamp +-65504). Grid-stride.
// ===========================================================================
__global__ void cvt_kernel(const float* __restrict__ in, bf16* __restrict__ out, int n) {
  for (int i = blockIdx.x * 256 + threadIdx.x; i < n; i += gridDim.x * 256) {
    float v = in[i];
    v = (v == v) ? fminf(fmaxf(v, -65504.f), 65504.f) : 0.f;
    out[i] = (bf16)v;
  }
}

// ===========================================================================
// GEMM: out[M,N] = A[M,K] @ W[N,K]^T (+bias), fused epilogues.
// Round-8 structure change: VGPR-prefetch pipeline. Round-7 PMC showed the
// global_load_lds path is drain-bound: vmcnt(0)+barrier per K-iter =>
// ~9.6k cyc/block-iter (96 KB staging issued-then-drained at ~24 GB/s/CU),
// MfmaUtil 17%. Now: tile k+1 is loaded into VGPRs during tile k's MFMA
// phase; ds_write next iter only waits its own vmcnt(N), never a full drain.
// Also: XCD-aware block swizzle — the N/128 blocks sharing an A-row-block
// land on one XCD => A-tile HBM-fetched once, L2-served after.
// 128x128 tile, BK=64, 4 waves (2x2 of 64x64), mfma_f32_16x16x32_bf16.
// XOR-swizzled LDS (round-6: SQ_LDS_BANK_CONFLICT == 0).
// MODE 0: out_bf16 = acc (+bias)
// MODE 1: out_f32  = acc + bias
// MODE 2: out_bf16 = acc + bias + extra_f32[off]
// MODE 3: out_bf16 = extra_bf16[off] * silu(acc)            (z-gate)
// MODE 4: out_f32  = acc + extra_bf16[off]                  (residual, final)
// MODE 5: out_bf16 = softplus(acc + bias)                   (delta)
// MODE 6: out_bf16 = extra_bf16[off] * (acc + bias)         (nla = delta*A_t)
// ===========================================================================
template<int MODE, bool HAS_BIAS, int N, int K>
__global__ __launch_bounds__(256, 3)
void gemm_bt(const bf16* __restrict__ A, const bf16* __restrict__ W,
             const float* __restrict__ bias, const void* __restrict__ extra,
             void* __restrict__ outp) {
  __shared__ __align__(16) bf16 lds_a[128*64];
  __shared__ __align__(16) bf16 lds_b[128*64];
  const int tid  = threadIdx.x;
  const int wave = tid >> 6;
  const int lane = tid & 63;
  const int wm = wave >> 1, wn = wave & 1;

  // XCD-aware swizzle: consecutive blockIdx round-robin XCDs (id&7); give
  // each XCD a contiguous bm range with bn fastest -> same-bm group shares
  // its XCD's L2 copy of the A-tiles. Bijective for gridDim.y % 8 == 0.
  constexpr int NBN = N / 128;
  const int nbm8 = (int)(gridDim.y >> 3);
  const int id   = (int)(blockIdx.y * NBN + blockIdx.x);
  const int xcd  = id & 7;
  const unsigned jj = (unsigned)id >> 3;
  const int bm   = xcd * nbm8 + (int)(jj / (unsigned)NBN);
  const int bn   = (int)(jj & (NBN - 1));

  const int r_in = lane >> 3;             // row within 8-row chunk
  const int kc_l = (lane & 7) ^ r_in;     // swizzle: this lane stages k-chunk c^r
  const size_t arow0 = (size_t)bm * 128;
  const size_t brow0 = (size_t)bn * 128;

  f32x4 acc[4][4];
#pragma unroll
  for (int i = 0; i < 4; ++i)
#pragma unroll
    for (int j = 0; j < 4; ++j) acc[i][j] = {0.f, 0.f, 0.f, 0.f};

  const int mrow = lane & 15;
  const int kg   = lane >> 4;

  // Per-lane staging pointers (K compile-time => strength-reduced bumps).
  const bf16* pa[4];
  const bf16* pb[4];
#pragma unroll
  for (int iss = 0; iss < 4; ++iss) {
    const int chunk = iss * 4 + wave;
    const int row   = chunk * 8 + r_in;
    pa[iss] = A + (arow0 + row) * (size_t)K + kc_l * 8;
    pb[iss] = W + (brow0 + row) * (size_t)K + kc_l * 8;
  }

  // Prologue: tile 0 -> VGPRs.
  bf16x8 va[4], vb[4];
#pragma unroll
  for (int iss = 0; iss < 4; ++iss) {
    va[iss] = *(const bf16x8*)pa[iss]; pa[iss] += 64;
    vb[iss] = *(const bf16x8*)pb[iss]; pb[iss] += 64;
  }

#pragma unroll 1
  for (int k0 = 0; k0 < K; k0 += 64) {
    __syncthreads();  // previous tile's LDS readers done before overwrite
#pragma unroll
    for (int iss = 0; iss < 4; ++iss) {
      const int chunk = iss * 4 + wave;
      *(bf16x8*)&lds_a[chunk * 512 + lane * 8] = va[iss];   // waits own vmcnt only
      *(bf16x8*)&lds_b[chunk * 512 + lane * 8] = vb[iss];
    }
    __syncthreads();  // LDS tile valid
    if (k0 + 64 < K) {      // prefetch tile k+1; lands during MFMA below
#pragma unroll
      for (int iss = 0; iss < 4; ++iss) {
        va[iss] = *(const bf16x8*)pa[iss]; pa[iss] += 64;
        vb[iss] = *(const bf16x8*)pb[iss]; pb[iss] += 64;
      }
    }
#pragma unroll
    for (int ks = 0; ks < 2; ++ks) {
      bf16x8 af[4], bfr[4];
#pragma unroll
      for (int t = 0; t < 4; ++t) {
        const int ra = wm * 64 + t * 16 + mrow;
        const int sa = ra * 8 + ((ks * 4 + kg) ^ (ra & 7));
        af[t] = *(const bf16x8*)&lds_a[sa * 8];
        const int rb = wn * 64 + t * 16 + mrow;
        const int sb = rb * 8 + ((ks * 4 + kg) ^ (rb & 7));
        bfr[t] = *(const bf16x8*)&lds_b[sb * 8];
      }
#pragma unroll
      for (int i = 0; i < 4; ++i)
#pragma unroll
        for (int j = 0; j < 4; ++j)
          acc[i][j] = __builtin_amdgcn_mfma_f32_16x16x32_bf16(af[i], bfr[j], acc[i][j], 0, 0, 0);
    }
  }

  // Epilogue. C/D layout: col = lane&15, row = (lane>>4)*4 + reg.
#pragma unroll
  for (int j = 0; j < 4; ++j) {
    const int col = bn * 128 + wn * 64 + j * 16 + mrow;
    float bv = 0.f;
    if constexpr (HAS_BIAS) bv = bias[col];
#pragma unroll
    for (int i = 0; i < 4; ++i) {
      const int row0 = bm * 128 + wm * 64 + i * 16 + kg * 4;
#pragma unroll
      for (int r = 0; r < 4; ++r) {
        const size_t off = (size_t)(row0 + r) * N + col;
        float v = acc[i][j][r] + bv;
        if constexpr (MODE == 0) {
          ((bf16*)outp)[off] = (bf16)v;
        } else if constexpr (MODE == 1) {
          ((float*)outp)[off] = v;
        } else if constexpr (MODE == 2) {
          ((bf16*)outp)[off] = (bf16)(v + ((const float*)extra)[off]);
        } else if constexpr (MODE == 3) {
          const float g = (float)((const bf16*)extra)[off];
          const float s = v / (1.f + expf(-v));
          ((bf16*)outp)[off] = (bf16)(g * s);
        } else if constexpr (MODE == 4) {
          ((float*)outp)[off] = v + (float)((const bf16*)extra)[off];
        } else if constexpr (MODE == 5) {
          const float sp = (v > 15.f) ? v : log1pf(expf(v));
          ((bf16*)outp)[off] = (bf16)sp;
        } else {  // MODE 6
          const float d = (float)((const bf16*)extra)[off];
          ((bf16*)outp)[off] = (bf16)(d * v);
        }
      }
    }
  }
}

// ===========================================================================
// depthwise conv1d(k=3, pad=1 along L, per-batch) + bias + silu. 8 d's/thread.
// ===========================================================================
__global__ void conv_silu_kernel(const bf16* __restrict__ t1, const float* __restrict__ cw,
                                 const float* __restrict__ cb, bf16* __restrict__ xc) {
  const int gid  = blockIdx.x * 256 + threadIdx.x;   // MT*DM/8 threads
  const int dgrp = gid & (DM / 8 - 1);
  const int bl   = gid >> 7;
  const int l    = bl & (SL - 1);
  const int d0   = dgrp * 8;
  const bf16* p  = t1 + (size_t)bl * DM + d0;
  bf16x8 cc = *(const bf16x8*)p;
  bf16x8 lf, rt;
#pragma unroll
  for (int j = 0; j < 8; ++j) { lf[j] = (bf16)0.f; rt[j] = (bf16)0.f; }
  if (l > 0)      lf = *(const bf16x8*)(p - DM);
  if (l < SL - 1) rt = *(const bf16x8*)(p + DM);
  bf16x8 o;
#pragma unroll
  for (int j = 0; j < 8; ++j) {
    const int d = d0 + j;
    float y = cw[d * 3 + 0] * (float)lf[j] + cw[d * 3 + 1] * (float)cc[j]
            + cw[d * 3 + 2] * (float)rt[j] + cb[d];
    y = y / (1.f + expf(-y));
    o[j] = (bf16)y;
  }
  *(bf16x8*)(xc + (size_t)bl * DM + d0) = o;
}

// ===========================================================================
// Parallel scan over L, 3 phases, chunked (LC=256, NC=16).
// h_l = sum_{i<=l} Bx_i * exp(-sum_{j<=i} nla_j).
// ===========================================================================
__global__ void scan_phase1(bf16* nla_sl, const bf16* __restrict__ bx,
                            float* __restrict__ Lp_tot, float* __restrict__ T_tot) {
  const int g  = blockIdx.x * 256 + threadIdx.x;   // 131072 threads
  const int ch = g & (DH - 1);
  const int rc = g >> 11;          // 0..63
  const int b  = rc & (NB - 1);
  const int c  = rc >> 2;          // 0..15
  const int bc = b * DH + ch;
  size_t off = ((size_t)(b * SL + c * LC)) * DH + ch;
  float lp = 0.f, S = 0.f;
#pragma unroll 8
  for (int l = 0; l < LC; ++l, off += DH) {
    const float a = (float)nla_sl[off];
    const float x = (float)bx[off];
    lp += a;
    const float e = __expf(-fminf(fmaxf(lp, -80.f), 80.f));
    S = fmaf(x, e, S);
    nla_sl[off] = (bf16)S;
  }
  Lp_tot[c * (NB * DH) + bc] = lp;
  T_tot [c * (NB * DH) + bc] = S;
}

__global__ void scan_phase2(const float* __restrict__ Lp_tot, const float* __restrict__ T_tot,
                            float* __restrict__ lpoff, float* __restrict__ Soff) {
  const int bc = blockIdx.x * 256 + threadIdx.x;   // 0..8191
  float lp = 0.f, S = 0.f;
#pragma unroll
  for (int c = 0; c < NC; ++c) {
    lpoff[c * (NB * DH) + bc] = lp;
    Soff [c * (NB * DH) + bc] = S;
    const float e = __expf(-fminf(fmaxf(lp, -80.f), 80.f));
    S  = fmaf(e, T_tot[c * (NB * DH) + bc], S);
    lp += Lp_tot[c * (NB * DH) + bc];
  }
}

__global__ void scan_phase3(const bf16* __restrict__ S_local, bf16* __restrict__ h,
                            const float* __restrict__ lpoff, const float* __restrict__ Soff) {
  const int g  = blockIdx.x * 256 + threadIdx.x;
  const int ch = g & (DH - 1);
  const int rc = g >> 11;
  const int b  = rc & (NB - 1);
  const int c  = rc >> 2;
  const int bc = b * DH + ch;
  const float lo = lpoff[c * (NB * DH) + bc];
  const float so = Soff [c * (NB * DH) + bc];
  const float es = __expf(-fminf(fmaxf(lo, -80.f), 80.f));
  size_t off = ((size_t)(b * SL + c * LC)) * DH + ch;
#pragma unroll 8
  for (int l = 0; l < LC; ++l, off += DH) {
    h[off] = (bf16)fmaf(es, (float)S_local[off], so);
  }
}

// ===========================================================================
// Workspace (max live 186 MB <= proven-safe 192 MB), offsets in MB:
//  [  0.. 24): bf16 weights (persistent)
//  [ 24.. 56): xc -> ssm
//  [ 56..120): t1/xbf -> dlo -> bxh (Bx, then h) ; z
//  [120..184): nla -> S_local (in-place) -> dtmp (fp32)
//  [184..186): scan totals
// ===========================================================================
extern "C" void kernel_launch(void* const* d_in, const int* in_sizes, int n_in,
                              void* d_out, int out_size, void* d_ws, size_t ws_size,
                              hipStream_t stream) {
  const float* x    = (const float*)d_in[0];
  const float* w1   = (const float*)d_in[1];
  const float* w2   = (const float*)d_in[2];
  const float* w3   = (const float*)d_in[3];
  const float* cw   = (const float*)d_in[4];
  const float* cb   = (const float*)d_in[5];
  const float* A_w  = (const float*)d_in[6];
  const float* A_b  = (const float*)d_in[7];
  const float* B_w  = (const float*)d_in[8];
  const float* B_b  = (const float*)d_in[9];
  const float* C_w  = (const float*)d_in[10];
  const float* C_b  = (const float*)d_in[11];
  const float* D_w  = (const float*)d_in[12];
  const float* D_b  = (const float*)d_in[13];
  const float* dl_w = (const float*)d_in[14];
  const float* dl_b = (const float*)d_in[15];

  const size_t MB = 1048576u;
  char* ws = (char*)d_ws;
  bf16* w1b  = (bf16*)(ws + 0*MB);
  bf16* w2b  = (bf16*)(ws + 2*MB);
  bf16* w3b  = (bf16*)(ws + 4*MB);
  bf16* Dwb  = (bf16*)(ws + 6*MB);
  bf16* Awb  = (bf16*)(ws + 8*MB);
  bf16* Bwb  = (bf16*)(ws + 12*MB);
  bf16* dlwb = (bf16*)(ws + 16*MB);
  bf16* Cwb  = (bf16*)(ws + 20*MB);
  bf16* xc   = (bf16*)(ws + 24*MB);
  bf16* ssm  = xc;
  bf16* t1   = (bf16*)(ws + 56*MB);
  bf16* z    = t1;
  bf16* xbf  = (bf16*)(ws + 88*MB);
  bf16* dlo  = (bf16*)(ws + 56*MB);   // 64 MB region
  bf16* bxh  = dlo;                    // Bx, then h (phase3 writes)
  bf16* nla  = (bf16*)(ws + 120*MB);  // 64 MB; S_local in-place; then dtmp
  float* dtmp = (float*)nla;
  float* Lp_tot = (float*)(ws + 184*MB);
  float* T_tot  = (float*)(ws + 184*MB + 524288u);
  float* lpoff  = (float*)(ws + 185*MB);
  float* Soff   = (float*)(ws + 185*MB + 524288u);
  float* outp = (float*)d_out;

  dim3 blk(256);
  dim3 g1(DM / 128, MT / 128);   // N=1024
  dim3 g2(DH / 128, MT / 128);   // N=2048

  // --- convert inputs to bf16 (sanitizing) ---
  cvt_kernel<<<4096, blk, 0, stream>>>(x,    xbf,  MT*DM);
  cvt_kernel<<<512,  blk, 0, stream>>>(w1,   w1b,  DM*DM);
  cvt_kernel<<<512,  blk, 0, stream>>>(w2,   w2b,  DM*DM);
  cvt_kernel<<<512,  blk, 0, stream>>>(w3,   w3b,  DM*DM);
  cvt_kernel<<<512,  blk, 0, stream>>>(D_w,  Dwb,  DM*DM);
  cvt_kernel<<<1024, blk, 0, stream>>>(A_w,  Awb,  DH*DM);
  cvt_kernel<<<1024, blk, 0, stream>>>(B_w,  Bwb,  DH*DM);
  cvt_kernel<<<1024, blk, 0, stream>>>(dl_w, dlwb, DH*DM);
  cvt_kernel<<<1024, blk, 0, stream>>>(C_w,  Cwb,  DM*DH);

  // --- pipeline ---
  gemm_bt<0,false,DM,DM><<<g1, blk, 0, stream>>>(xbf, w1b,  nullptr, nullptr, t1);
  conv_silu_kernel<<<MT * DM / 8 / 256, blk, 0, stream>>>(t1, cw, cb, xc);
  gemm_bt<5,true ,DH,DM><<<g2, blk, 0, stream>>>(xc,  dlwb, dl_b,    nullptr, dlo);
  gemm_bt<6,true ,DH,DM><<<g2, blk, 0, stream>>>(xc,  Awb,  A_b,     dlo,     nla);
  gemm_bt<0,true ,DH,DM><<<g2, blk, 0, stream>>>(xc,  Bwb,  B_b,     nullptr, bxh);
  scan_phase1<<<MT * NC * DH / SL / 256, blk, 0, stream>>>(nla, bxh, Lp_tot, T_tot);
  scan_phase2<<<NB * DH / 256, blk, 0, stream>>>(Lp_tot, T_tot, lpoff, Soff);
  scan_phase3<<<MT * NC * DH / SL / 256, blk, 0, stream>>>(nla, bxh, lpoff, Soff);
  gemm_bt<1,true ,DM,DM><<<g1, blk, 0, stream>>>(xc,  Dwb,  D_b,     nullptr, dtmp);
  gemm_bt<2,true ,DM,DH><<<g1, blk, 0, stream>>>(bxh, Cwb,  C_b,     dtmp,    ssm);
  gemm_bt<3,false,DM,DM><<<g1, blk, 0, stream>>>(ssm, w2b,  nullptr, ssm,     z);
  gemm_bt<4,false,DM,DM><<<g1, blk, 0, stream>>>(z,   w3b,  nullptr, ssm,     outp);
}